// Round 8
// baseline (324.730 us; speedup 1.0000x reference)
//
#include <hip/hip_runtime.h>
#include <stdint.h>
#include <math.h>

typedef unsigned short u16;
typedef __attribute__((ext_vector_type(8))) short short8;
typedef __attribute__((ext_vector_type(8))) u16 ushort8;
typedef __attribute__((ext_vector_type(4))) u16 u16x4;
typedef __attribute__((ext_vector_type(4))) float floatx4;

__device__ __forceinline__ u16 f2bf(float f) {
  union { float f; unsigned u; } c; c.f = f;
  unsigned u = c.u;
  return (u16)((u + 0x7fffu + ((u >> 16) & 1u)) >> 16);
}
__device__ __forceinline__ float bf2f(u16 h) {
  union { unsigned u; float f; } c; c.u = (unsigned)h << 16;
  return c.f;
}

// async global->LDS, 16 bytes per lane; LDS dest must be lane-contiguous.
__device__ __forceinline__ void async16(const u16* g, u16* l) {
  auto* gp = reinterpret_cast<const __attribute__((address_space(1))) uint32_t*>(
      reinterpret_cast<uintptr_t>(g));
  auto* lp = reinterpret_cast<__attribute__((address_space(3))) uint32_t*>(
      reinterpret_cast<uintptr_t>(l));
  __builtin_amdgcn_global_load_lds(gp, lp, 16, 0, 0);
}

// s_waitcnt immediates (gfx9 encoding): vmcnt[3:0] | expcnt<<4 | lgkmcnt<<8
#define WAIT_VM4 0xF74  // vmcnt(4): wait until <=4 vmem ops outstanding
#define WAIT_VM0 0xF70  // vmcnt(0)

// ---------------------------------------------------------------------------
// C = A * B^T.  A: [M][K] bf16 row-major (lda), B: [N][K] bf16 row-major (ldb).
// 256 threads = 4 waves, 128x128 tile, per-wave 64x64.  ~4 blocks/CU ->
// wave-level overlap hides the barrier drain.
// Double-buffered LDS + vmcnt(4) pipeline.  16B-seg XOR swizzle.
// tri_grid: blockIdx.x enumerates lower-triangle tiles (S gemm), PLAIN order
//   (R6/R7's XCD swizzle measured ~+15-25us: with all 544 blocks co-resident
//   the remap only perturbs the wg->XCD packing, which is not the assumed
//   round-robin -> L2 thrash.  Reverted to R4 decode.)
// SPLITK (out gemm, template): grid.x = 24 slots:
//   bx 0..7   -> bm = 8+bx, K part [0,1024)    (heaviest first)
//   bx 8..15  -> bm = 15-(bx-8), K part [1024, klimit)
//   bx 16..23 -> bm = 23-bx (7..0), full K (single writer)
//   split tiles (bm>=8) have two writers -> unsafeAtomicAdd onto zeroed C.
//   (exact: fl(a+b) is order-independent for two addends on a zeroed base)
// vpt: z==2 writes C transposed as [4][1024][2048] (vp^T direct).
// ---------------------------------------------------------------------------
template <int OUT_BF16, int SPLITK>
__global__ __launch_bounds__(256) void gemm_bt(
    const u16* __restrict__ A, const u16* __restrict__ B, void* __restrict__ Cv,
    int K, int lda, int ldb, int ldc,
    long long sA, long long sB, long long sC,
    float scale, int tri_grid, int causal_klimit,
    int vpt, u16* __restrict__ vpC) {
  int bm, bn;
  int kt0 = 0;
  bool part0_heavy = false;
  bool atomic_out = false;
  if (tri_grid) {
    const int bx = blockIdx.x;
    int i = (int)((sqrtf(8.f * bx + 1.f) - 1.f) * 0.5f);
    while ((i + 1) * (i + 2) / 2 <= bx) ++i;
    while (i * (i + 1) / 2 > bx) --i;
    bm = i;
    bn = bx - i * (i + 1) / 2;
  } else if (SPLITK) {
    const int bx = blockIdx.x;  // 0..23
    if (bx < 8) {
      bm = 8 + bx; part0_heavy = true; atomic_out = true;
    } else if (bx < 16) {
      bm = 15 - (bx - 8); kt0 = 32; atomic_out = true;
    } else {
      bm = 23 - bx;
    }
    bn = blockIdx.y;
  } else {
    bm = blockIdx.x;
    bn = blockIdx.y;
  }
  const int m0 = bm * 128;
  const int n0 = bn * 128;
  A += (size_t)blockIdx.z * sA;
  B += (size_t)blockIdx.z * sB;

  __shared__ u16 As[2][4096];
  __shared__ u16 Bs[2][4096];

  const int tid = threadIdx.x;
  const int lane = tid & 63;
  const int wid = tid >> 6;
  const int wm = (wid & 1) * 64;
  const int wn = (wid >> 1) * 64;
  const int fr = lane & 15;   // m/n within 16x16 frag
  const int fq = lane >> 4;   // logical k-segment

  floatx4 acc[4][4] = {};

  int kt_end = K >> 5;
  if (causal_klimit) {
    int lim = (m0 >> 5) + 4;
    if (lim < kt_end) kt_end = lim;
  }
  if (part0_heavy && kt_end > 32) kt_end = 32;

  const int rowi = tid >> 2;                 // 0..63
  const int segi = tid & 3;                  // physical 16B seg
  const int sgz = segi ^ ((rowi >> 1) & 3);  // logical seg to fetch
  const u16* gA = A + (size_t)(m0 + rowi) * lda + sgz * 8;
  const u16* gB = B + (size_t)(n0 + rowi) * ldb + sgz * 8;

  // fragment read offsets (swizzled), within one 4096-elem buffer
  int offA[4], offB[4];
#pragma unroll
  for (int i = 0; i < 4; ++i) {
    int ra = wm + i * 16 + fr;
    offA[i] = ra * 32 + (fq ^ ((ra >> 1) & 3)) * 8;
    int rb = wn + i * 16 + fr;
    offB[i] = rb * 32 + (fq ^ ((rb >> 1) & 3)) * 8;
  }

  auto issue = [&](int kt) {
    const int k0 = kt << 5;
    const int odd = kt & 1;
    async16(gA + k0, &As[odd][tid * 8]);
    async16(gA + k0 + (size_t)64 * lda, &As[odd][tid * 8 + 2048]);
    async16(gB + k0, &Bs[odd][tid * 8]);
    async16(gB + k0 + (size_t)64 * ldb, &Bs[odd][tid * 8 + 2048]);
  };

  issue(kt0);
  for (int kt = kt0; kt < kt_end; ++kt) {
    if (kt + 1 < kt_end) {
      issue(kt + 1);
      __builtin_amdgcn_s_waitcnt(WAIT_VM4);  // tile kt's 4 loads retired
    } else {
      __builtin_amdgcn_s_waitcnt(WAIT_VM0);
    }
    asm volatile("s_barrier" ::: "memory");

    const u16* ab = As[kt & 1];
    const u16* bb = Bs[kt & 1];
    short8 av[4], bv[4];
#pragma unroll
    for (int i = 0; i < 4; ++i) av[i] = *(const short8*)(ab + offA[i]);
#pragma unroll
    for (int j = 0; j < 4; ++j) bv[j] = *(const short8*)(bb + offB[j]);

#pragma unroll
    for (int i = 0; i < 4; ++i)
#pragma unroll
      for (int j = 0; j < 4; ++j)
        acc[i][j] = __builtin_amdgcn_mfma_f32_16x16x32_bf16(av[i], bv[j],
                                                            acc[i][j], 0, 0, 0);
    asm volatile("s_barrier" ::: "memory");  // readers done before overwrite
  }

  // Epilogue. C/D layout: col = lane&15 (=fr), row = fq*4 + reg.
  if (vpt && blockIdx.z == 2) {
    // write transposed: vpC[b][n][t], b = m>>11, t = m&2047 (T=2048, H=1024)
#pragma unroll
    for (int i = 0; i < 4; ++i) {
      const int m = m0 + wm + i * 16 + fq * 4;
      const int b = m >> 11, t = m & 2047;
#pragma unroll
      for (int j = 0; j < 4; ++j) {
        const int n = n0 + wn + j * 16 + fr;
        u16x4 o;
#pragma unroll
        for (int r = 0; r < 4; ++r) o[r] = f2bf(acc[i][j][r]);
        *(u16x4*)&vpC[(size_t)b * 2097152 + (size_t)n * 2048 + t] = o;
      }
    }
    return;
  }
  if (OUT_BF16) {
    u16* C = (u16*)Cv + (size_t)blockIdx.z * sC;
#pragma unroll
    for (int i = 0; i < 4; ++i) {
      const int m = m0 + wm + i * 16 + fq * 4;
#pragma unroll
      for (int j = 0; j < 4; ++j) {
        const int n = n0 + wn + j * 16 + fr;
#pragma unroll
        for (int r = 0; r < 4; ++r)
          C[(size_t)(m + r) * ldc + n] = f2bf(acc[i][j][r] * scale);
      }
    }
  } else {
    float* C = (float*)Cv + (size_t)blockIdx.z * sC;
    if (SPLITK && atomic_out) {
#pragma unroll
      for (int i = 0; i < 4; ++i) {
        const int m = m0 + wm + i * 16 + fq * 4;
#pragma unroll
        for (int j = 0; j < 4; ++j) {
          const int n = n0 + wn + j * 16 + fr;
#pragma unroll
          for (int r = 0; r < 4; ++r)
            unsafeAtomicAdd(&C[(size_t)(m + r) * ldc + n],
                            acc[i][j][r] * scale);
        }
      }
    } else {
#pragma unroll
      for (int i = 0; i < 4; ++i) {
        const int m = m0 + wm + i * 16 + fq * 4;
#pragma unroll
        for (int j = 0; j < 4; ++j) {
          const int n = n0 + wn + j * 16 + fr;
#pragma unroll
          for (int r = 0; r < 4; ++r)
            C[(size_t)(m + r) * ldc + n] = acc[i][j][r] * scale;
        }
      }
    }
  }
}

// ---------------------------------------------------------------------------
// Fused prep: ONE dispatch for
//   blocks [0, 12288):      cast q,k,v fp32->bf16 (4096 blocks each)
//   blocks [12288, 13056):  W transpose+cast (Wq,Wk,Wq -> [H][C], 256 ea)
//   blocks [13056, 17152):  zero split-K atomic region out[z][1024:2048][:]
// All parts independent, memory-bound; fusing removes 2 dispatch gaps.
// ---------------------------------------------------------------------------
__global__ __launch_bounds__(256) void prep(
    const float* __restrict__ q, const float* __restrict__ k,
    const float* __restrict__ v, const float* __restrict__ Wq,
    const float* __restrict__ Wk, u16* __restrict__ qkv,
    u16* __restrict__ WT, float* __restrict__ out) {
  __shared__ u16 tile[64][72];
  const int bx = blockIdx.x;
  const int tid = threadIdx.x;

  if (bx < 12288) {  // ---- cast q/k/v: 4096 blocks per source ----
    const int z = bx >> 12;            // 0..2
    const int i = (bx & 4095) * 256 + tid;  // ushort8 index, n8 = 1048576
    const float* src = z == 0 ? q : (z == 1 ? k : v);
    u16* dst = qkv + (size_t)z * 8388608;
    floatx4 a = ((const floatx4*)src)[i * 2];
    floatx4 b = ((const floatx4*)src)[i * 2 + 1];
    ushort8 o;
#pragma unroll
    for (int j = 0; j < 4; ++j) { o[j] = f2bf(a[j]); o[4 + j] = f2bf(b[j]); }
    ((ushort8*)dst)[i] = o;
    return;
  }
  if (bx < 13056) {  // ---- W transpose: 256 blocks per W slot ----
    const int idx = bx - 12288;
    const int zw = idx >> 8;           // 0..2 (Wq, Wk, Wq)
    const int rem = idx & 255;
    const int r0 = (rem >> 4) * 64;    // C/64 = 16
    const int c0 = (rem & 15) * 64;    // H/64 = 16
    const int R = 1024, C = 1024;
    const float* in = (zw == 1) ? Wk : Wq;
    u16* dst = WT + (size_t)zw * R * C;
#pragma unroll
    for (int rnd = 0; rnd < 2; ++rnd) {
      int e = rnd * 256 + tid;
      int rr = e >> 3, seg = e & 7;
      const float* p = &in[(size_t)(r0 + rr) * C + c0 + seg * 8];
      floatx4 a = *(const floatx4*)p;
      floatx4 b = *(const floatx4*)(p + 4);
      u16* tp = &tile[rr][seg * 8];
#pragma unroll
      for (int j = 0; j < 4; ++j) { tp[j] = f2bf(a[j]); tp[4 + j] = f2bf(b[j]); }
    }
    __syncthreads();
#pragma unroll
    for (int rnd = 0; rnd < 2; ++rnd) {
      int e = rnd * 256 + tid;
      int cc = e >> 3, rseg = e & 7;
      ushort8 tv;
#pragma unroll
      for (int j = 0; j < 8; ++j) tv[j] = tile[rseg * 8 + j][cc];
      *(ushort8*)&dst[(size_t)(c0 + cc) * R + r0 + rseg * 8] = tv;
    }
    return;
  }
  {  // ---- zero split-K atomic region: 4096 blocks ----
    const size_t i = (size_t)(bx - 13056) * 256 + tid;  // float4 index
    const size_t z = i >> 18;          // 262144 float4 per batch-half
    const size_t r = i & 262143;
    floatx4* p = (floatx4*)(out + z * 2097152 + 1048576) + r;
    *p = floatx4{0.f, 0.f, 0.f, 0.f};
  }
}

// Causal row softmax, bf16 in-place, ONE WAVE PER ROW (T=2048).
// 4 rows per 256-thread block; each wave: 4x ushort8 load (lane-contiguous
// 512B chunks), per-lane causal mask, 6-step shfl_xor max+sum reduce, 4x
// ushort8 store.  No LDS, no barriers, all locals statically indexed.
// Masked lanes store exp(-huge)*inv = 0 -> upper-triangle zero-fill.
__global__ __launch_bounds__(256) void softmax_causal(u16* __restrict__ S,
                                                      int T) {
  const int row = blockIdx.x * 4 + (threadIdx.x >> 6);
  const int t = row & (T - 1);
  const int len = t + 1;
  u16* srow = S + (size_t)row * T;
  const int lane = threadIdx.x & 63;

  ushort8 raw0 = *(const ushort8*)(srow + (lane) * 8);
  ushort8 raw1 = *(const ushort8*)(srow + (64 + lane) * 8);
  ushort8 raw2 = *(const ushort8*)(srow + (128 + lane) * 8);
  ushort8 raw3 = *(const ushort8*)(srow + (192 + lane) * 8);

  float v0[8], v1[8], v2[8], v3[8];
  float mx = -1e30f;
#pragma unroll
  for (int j = 0; j < 8; ++j) {
    const int i0 = lane * 8 + j;
    v0[j] = (i0 < len) ? bf2f(raw0[j]) : -1e30f;
    v1[j] = (i0 + 512 < len) ? bf2f(raw1[j]) : -1e30f;
    v2[j] = (i0 + 1024 < len) ? bf2f(raw2[j]) : -1e30f;
    v3[j] = (i0 + 1536 < len) ? bf2f(raw3[j]) : -1e30f;
    mx = fmaxf(mx, fmaxf(fmaxf(v0[j], v1[j]), fmaxf(v2[j], v3[j])));
  }
#pragma unroll
  for (int o = 32; o > 0; o >>= 1) mx = fmaxf(mx, __shfl_xor(mx, o, 64));

  float sum = 0.f;
#pragma unroll
  for (int j = 0; j < 8; ++j) {
    v0[j] = __expf(v0[j] - mx); sum += v0[j];
    v1[j] = __expf(v1[j] - mx); sum += v1[j];
    v2[j] = __expf(v2[j] - mx); sum += v2[j];
    v3[j] = __expf(v3[j] - mx); sum += v3[j];
  }
#pragma unroll
  for (int o = 32; o > 0; o >>= 1) sum += __shfl_xor(sum, o, 64);
  const float inv = 1.f / sum;

  ushort8 o0, o1, o2, o3;
#pragma unroll
  for (int j = 0; j < 8; ++j) {
    o0[j] = f2bf(v0[j] * inv);
    o1[j] = f2bf(v1[j] * inv);
    o2[j] = f2bf(v2[j] * inv);
    o3[j] = f2bf(v3[j] * inv);
  }
  *(ushort8*)(srow + (lane) * 8) = o0;
  *(ushort8*)(srow + (64 + lane) * 8) = o1;
  *(ushort8*)(srow + (128 + lane) * 8) = o2;
  *(ushort8*)(srow + (192 + lane) * 8) = o3;
}

extern "C" void kernel_launch(void* const* d_in, const int* in_sizes, int n_in,
                              void* d_out, int out_size, void* d_ws,
                              size_t ws_size, hipStream_t stream) {
  (void)in_sizes; (void)n_in; (void)out_size; (void)ws_size;
  const float* k  = (const float*)d_in[1];
  const float* q  = (const float*)d_in[2];
  const float* v  = (const float*)d_in[3];
  const float* Wk = (const float*)d_in[4];
  const float* Wq = (const float*)d_in[5];
  float* out = (float*)d_out;

  const int B = 4, T = 2048, C = 1024, H = 1024;
  const int M = B * T;  // 8192
  const size_t MC = (size_t)M * C, CH = (size_t)C * H, MH = (size_t)M * H;

  u16* qkv  = (u16*)d_ws;        // 3 slots [M][C] bf16 (q,k,v)        50 MB
  u16* WT   = qkv + 3 * MC;      // 3 slots [H][C] bf16 (Wq,Wk,Wq)      6 MB
  u16* qkvp = WT + 3 * CH;       // slot0 qp, slot1 kp [M][H]          34 MB
  u16* vpT  = qkvp + 2 * MH;     // [B][H][T] bf16 (vp^T, direct)      17 MB
  u16* Sb   = vpT + MH;          // [B][T][T] bf16 (S, then P)       33.5 MB

  // 1) fused prep: cast q/k/v + W transposes + split-K zero (one dispatch)
  prep<<<dim3(17152), 256, 0, stream>>>(q, k, v, Wq, Wk, qkv, WT, out);

  // 2) qp = q*Wq, kp = k*Wk, vp^T = (v*Wq)^T (one batched dispatch, z=0..2)
  gemm_bt<1, 0><<<dim3(M / 128, H / 128, 3), 256, 0, stream>>>(
      qkv, WT, qkvp, C, C, C, H,
      (long long)MC, (long long)CH, (long long)MH, 1.f, 0, 0, 1, vpT);

  // 3) S = qp*kp^T / 32 (bf16), compact lower-triangle grid (plain order)
  gemm_bt<1, 0><<<dim3(136, 1, B), 256, 0, stream>>>(
      qkvp, qkvp + MH, Sb, H, H, H, T,
      (long long)T * H, (long long)T * H, (long long)T * T,
      0.03125f, 1, 0, 0, nullptr);

  // 4) causal softmax in-place (1 wave/row, 4 rows/block)
  softmax_causal<<<dim3(B * T / 4), 256, 0, stream>>>(Sb, T);

  // 5) out = P * vpT^T, causal klimit, split-K (24 slots: heavy halves first)
  gemm_bt<0, 1><<<dim3(24, H / 128, B), 256, 0, stream>>>(
      Sb, vpT, out, T, T, T, H,
      (long long)T * T, (long long)H * T, (long long)T * H,
      1.f, 0, 1, 0, nullptr);
}

// Round 9
// 307.489 us; speedup vs baseline: 1.0561x; 1.0561x over previous
//
#include <hip/hip_runtime.h>
#include <stdint.h>
#include <math.h>

typedef unsigned short u16;
typedef __attribute__((ext_vector_type(8))) short short8;
typedef __attribute__((ext_vector_type(8))) u16 ushort8;
typedef __attribute__((ext_vector_type(4))) u16 u16x4;
typedef __attribute__((ext_vector_type(4))) float floatx4;

__device__ __forceinline__ u16 f2bf(float f) {
  union { float f; unsigned u; } c; c.f = f;
  unsigned u = c.u;
  return (u16)((u + 0x7fffu + ((u >> 16) & 1u)) >> 16);
}
__device__ __forceinline__ float bf2f(u16 h) {
  union { unsigned u; float f; } c; c.u = (unsigned)h << 16;
  return c.f;
}

// async global->LDS, 16 bytes per lane; LDS dest must be lane-contiguous.
__device__ __forceinline__ void async16(const u16* g, u16* l) {
  auto* gp = reinterpret_cast<const __attribute__((address_space(1))) uint32_t*>(
      reinterpret_cast<uintptr_t>(g));
  auto* lp = reinterpret_cast<__attribute__((address_space(3))) uint32_t*>(
      reinterpret_cast<uintptr_t>(l));
  __builtin_amdgcn_global_load_lds(gp, lp, 16, 0, 0);
}

// s_waitcnt immediates (gfx9 encoding): vmcnt[3:0] | expcnt<<4 | lgkmcnt<<8
#define WAIT_VM4 0xF74  // vmcnt(4): wait until <=4 vmem ops outstanding
#define WAIT_VM0 0xF70  // vmcnt(0)

// ---------------------------------------------------------------------------
// C = A * B^T.  A: [M][K] bf16 row-major (lda), B: [N][K] bf16 row-major (ldb).
// 256 threads = 4 waves, 128x128 tile, per-wave 64x64.  ~4 blocks/CU ->
// wave-level overlap hides the barrier drain.
// Double-buffered LDS + vmcnt(4) pipeline.  16B-seg XOR swizzle.
// tri_grid: blockIdx.x enumerates lower-triangle tiles (S gemm), with the
//   bijective XCD swizzle (136 = 8 XCDs x 17 chunks) — R8 measured its
//   removal as a ~6us regression; restored.
// SPLITK (out gemm, template): grid.x = 24 slots:
//   bx 0..7   -> bm = 8+bx, K part [0,1024)    (heaviest first)
//   bx 8..15  -> bm = 15-(bx-8), K part [1024, klimit)
//   bx 16..23 -> bm = 23-bx (7..0), full K (single writer)
//   split tiles (bm>=8) have two writers -> unsafeAtomicAdd onto zeroed C.
//   (exact: fl(a+b) is order-independent for two addends on a zeroed base)
// vpt: blockIdx.z == vpt writes C transposed as [4][1024][2048] (vp^T);
//   vpt = 0 disables.
// ---------------------------------------------------------------------------
template <int OUT_BF16, int SPLITK>
__global__ __launch_bounds__(256) void gemm_bt(
    const u16* __restrict__ A, const u16* __restrict__ B, void* __restrict__ Cv,
    int K, int lda, int ldb, int ldc,
    long long sA, long long sB, long long sC,
    float scale, int tri_grid, int causal_klimit,
    int vpt, u16* __restrict__ vpC) {
  int bm, bn;
  int kt0 = 0;
  bool part0_heavy = false;
  bool atomic_out = false;
  if (tri_grid) {
    int bx = blockIdx.x;
    bx = (bx & 7) * 17 + (bx >> 3);  // bijective XCD swizzle (136 = 8*17)
    int i = (int)((sqrtf(8.f * bx + 1.f) - 1.f) * 0.5f);
    while ((i + 1) * (i + 2) / 2 <= bx) ++i;
    while (i * (i + 1) / 2 > bx) --i;
    bm = i;
    bn = bx - i * (i + 1) / 2;
  } else if (SPLITK) {
    const int bx = blockIdx.x;  // 0..23
    if (bx < 8) {
      bm = 8 + bx; part0_heavy = true; atomic_out = true;
    } else if (bx < 16) {
      bm = 15 - (bx - 8); kt0 = 32; atomic_out = true;
    } else {
      bm = 23 - bx;
    }
    bn = blockIdx.y;
  } else {
    bm = blockIdx.x;
    bn = blockIdx.y;
  }
  const int m0 = bm * 128;
  const int n0 = bn * 128;
  A += (size_t)blockIdx.z * sA;
  B += (size_t)blockIdx.z * sB;

  __shared__ u16 As[2][4096];
  __shared__ u16 Bs[2][4096];

  const int tid = threadIdx.x;
  const int lane = tid & 63;
  const int wid = tid >> 6;
  const int wm = (wid & 1) * 64;
  const int wn = (wid >> 1) * 64;
  const int fr = lane & 15;   // m/n within 16x16 frag
  const int fq = lane >> 4;   // logical k-segment

  floatx4 acc[4][4] = {};

  int kt_end = K >> 5;
  if (causal_klimit) {
    int lim = (m0 >> 5) + 4;
    if (lim < kt_end) kt_end = lim;
  }
  if (part0_heavy && kt_end > 32) kt_end = 32;

  const int rowi = tid >> 2;                 // 0..63
  const int segi = tid & 3;                  // physical 16B seg
  const int sgz = segi ^ ((rowi >> 1) & 3);  // logical seg to fetch
  const u16* gA = A + (size_t)(m0 + rowi) * lda + sgz * 8;
  const u16* gB = B + (size_t)(n0 + rowi) * ldb + sgz * 8;

  // fragment read offsets (swizzled), within one 4096-elem buffer
  int offA[4], offB[4];
#pragma unroll
  for (int i = 0; i < 4; ++i) {
    int ra = wm + i * 16 + fr;
    offA[i] = ra * 32 + (fq ^ ((ra >> 1) & 3)) * 8;
    int rb = wn + i * 16 + fr;
    offB[i] = rb * 32 + (fq ^ ((rb >> 1) & 3)) * 8;
  }

  auto issue = [&](int kt) {
    const int k0 = kt << 5;
    const int odd = kt & 1;
    async16(gA + k0, &As[odd][tid * 8]);
    async16(gA + k0 + (size_t)64 * lda, &As[odd][tid * 8 + 2048]);
    async16(gB + k0, &Bs[odd][tid * 8]);
    async16(gB + k0 + (size_t)64 * ldb, &Bs[odd][tid * 8 + 2048]);
  };

  issue(kt0);
  for (int kt = kt0; kt < kt_end; ++kt) {
    if (kt + 1 < kt_end) {
      issue(kt + 1);
      __builtin_amdgcn_s_waitcnt(WAIT_VM4);  // tile kt's 4 loads retired
    } else {
      __builtin_amdgcn_s_waitcnt(WAIT_VM0);
    }
    asm volatile("s_barrier" ::: "memory");

    const u16* ab = As[kt & 1];
    const u16* bb = Bs[kt & 1];
    short8 av[4], bv[4];
#pragma unroll
    for (int i = 0; i < 4; ++i) av[i] = *(const short8*)(ab + offA[i]);
#pragma unroll
    for (int j = 0; j < 4; ++j) bv[j] = *(const short8*)(bb + offB[j]);

#pragma unroll
    for (int i = 0; i < 4; ++i)
#pragma unroll
      for (int j = 0; j < 4; ++j)
        acc[i][j] = __builtin_amdgcn_mfma_f32_16x16x32_bf16(av[i], bv[j],
                                                            acc[i][j], 0, 0, 0);
    asm volatile("s_barrier" ::: "memory");  // readers done before overwrite
  }

  // Epilogue. C/D layout: col = lane&15 (=fr), row = fq*4 + reg.
  if (vpt && (int)blockIdx.z == vpt) {
    // write transposed: vpC[b][n][t], b = m>>11, t = m&2047 (T=2048, H=1024)
#pragma unroll
    for (int i = 0; i < 4; ++i) {
      const int m = m0 + wm + i * 16 + fq * 4;
      const int b = m >> 11, t = m & 2047;
#pragma unroll
      for (int j = 0; j < 4; ++j) {
        const int n = n0 + wn + j * 16 + fr;
        u16x4 o;
#pragma unroll
        for (int r = 0; r < 4; ++r) o[r] = f2bf(acc[i][j][r]);
        *(u16x4*)&vpC[(size_t)b * 2097152 + (size_t)n * 2048 + t] = o;
      }
    }
    return;
  }
  if (OUT_BF16) {
    u16* C = (u16*)Cv + (size_t)blockIdx.z * sC;
#pragma unroll
    for (int i = 0; i < 4; ++i) {
      const int m = m0 + wm + i * 16 + fq * 4;
#pragma unroll
      for (int j = 0; j < 4; ++j) {
        const int n = n0 + wn + j * 16 + fr;
#pragma unroll
        for (int r = 0; r < 4; ++r)
          C[(size_t)(m + r) * ldc + n] = f2bf(acc[i][j][r] * scale);
      }
    }
  } else {
    float* C = (float*)Cv + (size_t)blockIdx.z * sC;
    if (SPLITK && atomic_out) {
#pragma unroll
      for (int i = 0; i < 4; ++i) {
        const int m = m0 + wm + i * 16 + fq * 4;
#pragma unroll
        for (int j = 0; j < 4; ++j) {
          const int n = n0 + wn + j * 16 + fr;
#pragma unroll
          for (int r = 0; r < 4; ++r)
            unsafeAtomicAdd(&C[(size_t)(m + r) * ldc + n],
                            acc[i][j][r] * scale);
        }
      }
    } else {
#pragma unroll
      for (int i = 0; i < 4; ++i) {
        const int m = m0 + wm + i * 16 + fq * 4;
#pragma unroll
        for (int j = 0; j < 4; ++j) {
          const int n = n0 + wn + j * 16 + fr;
#pragma unroll
          for (int r = 0; r < 4; ++r)
            C[(size_t)(m + r) * ldc + n] = acc[i][j][r] * scale;
        }
      }
    }
  }
}

// ---------------------------------------------------------------------------
// Fused prep: ONE dispatch for
//   [0, 12288):      cast q,k,v fp32->bf16 (4096 blocks each)
//   [12288, 13312):  plain cast Wq,Wk -> bf16 [C][H] (512 blocks each)
//   [13312, 13568):  Wq transpose+cast -> WqT [H][C] (256 blocks, for vp)
//   [13568, 17664):  zero split-K atomic region out[z][1024:2048][:]
// WT layout (CH = 1024*1024 each): [0]=WqkT (written later by the Wqk GEMM),
//   [1]=WqT, [2]=Wq plain, [3]=Wk plain.
// ---------------------------------------------------------------------------
__global__ __launch_bounds__(256) void prep(
    const float* __restrict__ q, const float* __restrict__ k,
    const float* __restrict__ v, const float* __restrict__ Wq,
    const float* __restrict__ Wk, u16* __restrict__ qkv,
    u16* __restrict__ WT, float* __restrict__ out) {
  __shared__ u16 tile[64][72];
  const int bx = blockIdx.x;
  const int tid = threadIdx.x;

  if (bx < 12288) {  // ---- cast q/k/v: 4096 blocks per source ----
    const int z = bx >> 12;            // 0..2
    const int i = (bx & 4095) * 256 + tid;  // ushort8 index, n8 = 1048576
    const float* src = z == 0 ? q : (z == 1 ? k : v);
    u16* dst = qkv + (size_t)z * 8388608;
    floatx4 a = ((const floatx4*)src)[i * 2];
    floatx4 b = ((const floatx4*)src)[i * 2 + 1];
    ushort8 o;
#pragma unroll
    for (int j = 0; j < 4; ++j) { o[j] = f2bf(a[j]); o[4 + j] = f2bf(b[j]); }
    ((ushort8*)dst)[i] = o;
    return;
  }
  if (bx < 13312) {  // ---- plain cast Wq,Wk: 512 blocks each ----
    const int idx = bx - 12288;
    const int w = idx >> 9;            // 0=Wq, 1=Wk
    const int i = (idx & 511) * 256 + tid;  // ushort8 index, 131072 per W
    const float* src = w ? Wk : Wq;
    u16* dst = WT + (size_t)(2 + w) * 1048576;
    floatx4 a = ((const floatx4*)src)[i * 2];
    floatx4 b = ((const floatx4*)src)[i * 2 + 1];
    ushort8 o;
#pragma unroll
    for (int j = 0; j < 4; ++j) { o[j] = f2bf(a[j]); o[4 + j] = f2bf(b[j]); }
    ((ushort8*)dst)[i] = o;
    return;
  }
  if (bx < 13568) {  // ---- Wq transpose: 256 blocks -> WqT ----
    const int rem = bx - 13312;
    const int r0 = (rem >> 4) * 64;    // C/64 = 16
    const int c0 = (rem & 15) * 64;    // H/64 = 16
    const int R = 1024, C = 1024;
    const float* in = Wq;
    u16* dst = WT + 1048576;
#pragma unroll
    for (int rnd = 0; rnd < 2; ++rnd) {
      int e = rnd * 256 + tid;
      int rr = e >> 3, seg = e & 7;
      const float* p = &in[(size_t)(r0 + rr) * C + c0 + seg * 8];
      floatx4 a = *(const floatx4*)p;
      floatx4 b = *(const floatx4*)(p + 4);
      u16* tp = &tile[rr][seg * 8];
#pragma unroll
      for (int j = 0; j < 4; ++j) { tp[j] = f2bf(a[j]); tp[4 + j] = f2bf(b[j]); }
    }
    __syncthreads();
#pragma unroll
    for (int rnd = 0; rnd < 2; ++rnd) {
      int e = rnd * 256 + tid;
      int cc = e >> 3, rseg = e & 7;
      ushort8 tv;
#pragma unroll
      for (int j = 0; j < 8; ++j) tv[j] = tile[rseg * 8 + j][cc];
      *(ushort8*)&dst[(size_t)(c0 + cc) * R + r0 + rseg * 8] = tv;
    }
    return;
  }
  {  // ---- zero split-K atomic region: 4096 blocks ----
    const size_t i = (size_t)(bx - 13568) * 256 + tid;  // float4 index
    const size_t z = i >> 18;          // 262144 float4 per batch-half
    const size_t r = i & 262143;
    floatx4* p = (floatx4*)(out + z * 2097152 + 1048576) + r;
    *p = floatx4{0.f, 0.f, 0.f, 0.f};
  }
}

// Causal row softmax, bf16 in-place, ONE WAVE PER ROW (T=2048).
// 4 rows per 256-thread block; no LDS, no barriers, static locals only.
// Masked lanes store exp(-huge)*inv = 0 -> upper-triangle zero-fill.
__global__ __launch_bounds__(256) void softmax_causal(u16* __restrict__ S,
                                                      int T) {
  const int row = blockIdx.x * 4 + (threadIdx.x >> 6);
  const int t = row & (T - 1);
  const int len = t + 1;
  u16* srow = S + (size_t)row * T;
  const int lane = threadIdx.x & 63;

  ushort8 raw0 = *(const ushort8*)(srow + (lane) * 8);
  ushort8 raw1 = *(const ushort8*)(srow + (64 + lane) * 8);
  ushort8 raw2 = *(const ushort8*)(srow + (128 + lane) * 8);
  ushort8 raw3 = *(const ushort8*)(srow + (192 + lane) * 8);

  float v0[8], v1[8], v2[8], v3[8];
  float mx = -1e30f;
#pragma unroll
  for (int j = 0; j < 8; ++j) {
    const int i0 = lane * 8 + j;
    v0[j] = (i0 < len) ? bf2f(raw0[j]) : -1e30f;
    v1[j] = (i0 + 512 < len) ? bf2f(raw1[j]) : -1e30f;
    v2[j] = (i0 + 1024 < len) ? bf2f(raw2[j]) : -1e30f;
    v3[j] = (i0 + 1536 < len) ? bf2f(raw3[j]) : -1e30f;
    mx = fmaxf(mx, fmaxf(fmaxf(v0[j], v1[j]), fmaxf(v2[j], v3[j])));
  }
#pragma unroll
  for (int o = 32; o > 0; o >>= 1) mx = fmaxf(mx, __shfl_xor(mx, o, 64));

  float sum = 0.f;
#pragma unroll
  for (int j = 0; j < 8; ++j) {
    v0[j] = __expf(v0[j] - mx); sum += v0[j];
    v1[j] = __expf(v1[j] - mx); sum += v1[j];
    v2[j] = __expf(v2[j] - mx); sum += v2[j];
    v3[j] = __expf(v3[j] - mx); sum += v3[j];
  }
#pragma unroll
  for (int o = 32; o > 0; o >>= 1) sum += __shfl_xor(sum, o, 64);
  const float inv = 1.f / sum;

  ushort8 o0, o1, o2, o3;
#pragma unroll
  for (int j = 0; j < 8; ++j) {
    o0[j] = f2bf(v0[j] * inv);
    o1[j] = f2bf(v1[j] * inv);
    o2[j] = f2bf(v2[j] * inv);
    o3[j] = f2bf(v3[j] * inv);
  }
  *(ushort8*)(srow + (lane) * 8) = o0;
  *(ushort8*)(srow + (64 + lane) * 8) = o1;
  *(ushort8*)(srow + (128 + lane) * 8) = o2;
  *(ushort8*)(srow + (192 + lane) * 8) = o3;
}

extern "C" void kernel_launch(void* const* d_in, const int* in_sizes, int n_in,
                              void* d_out, int out_size, void* d_ws,
                              size_t ws_size, hipStream_t stream) {
  (void)in_sizes; (void)n_in; (void)out_size; (void)ws_size;
  const float* k  = (const float*)d_in[1];
  const float* q  = (const float*)d_in[2];
  const float* v  = (const float*)d_in[3];
  const float* Wk = (const float*)d_in[4];
  const float* Wq = (const float*)d_in[5];
  float* out = (float*)d_out;

  const int B = 4, T = 2048, C = 1024, H = 1024;
  const int M = B * T;  // 8192
  const size_t MC = (size_t)M * C, CH = (size_t)C * H, MH = (size_t)M * H;

  u16* qkv  = (u16*)d_ws;        // 3 slots [M][C] bf16 (q,k,v)        50 MB
  u16* WT   = qkv + 3 * MC;      // 4 slots: WqkT, WqT, Wq, Wk          8 MB
  u16* qkvp = WT + 4 * CH;       // qp' [M][H]                         17 MB
  u16* vpT  = qkvp + MH;         // [B][H][T] bf16 (vp^T, direct)      17 MB
  u16* Sb   = vpT + MH;          // [B][T][T] bf16 (S, then P)       33.5 MB

  // 1) fused prep: cast q/k/v, cast Wq/Wk, Wq transpose, split-K zero
  prep<<<dim3(17664), 256, 0, stream>>>(q, k, v, Wq, Wk, qkv, WT, out);

  // 2) Wqk^T = Wk * Wq^T (bf16, 1024^3, 64 tiles) — enables skipping kp:
  //    S = (q Wq)(k Wk)^T = (q Wqk) k^T
  gemm_bt<1, 0><<<dim3(8, 8, 1), 256, 0, stream>>>(
      WT + 3 * CH, WT + 2 * CH, WT, C, C, C, C,
      0, 0, 0, 1.f, 0, 0, 0, nullptr);

  // 3) z=0: qp' = q * Wqk (B = WqkT); z=1: vp^T = (v * Wq)^T (B = WqT)
  gemm_bt<1, 0><<<dim3(M / 128, H / 128, 2), 256, 0, stream>>>(
      qkv, WT, qkvp, C, C, C, H,
      (long long)(2 * MC), (long long)CH, 0, 1.f, 0, 0, 1, vpT);

  // 4) S = qp' * k^T / 32 (bf16), tri grid + XCD swizzle (restored)
  gemm_bt<1, 0><<<dim3(136, 1, B), 256, 0, stream>>>(
      qkvp, qkv + MC, Sb, C, H, C, T,
      (long long)T * H, (long long)T * C, (long long)T * T,
      0.03125f, 1, 0, 0, nullptr);

  // 5) causal softmax in-place (1 wave/row, 4 rows/block)
  softmax_causal<<<dim3(B * T / 4), 256, 0, stream>>>(Sb, T);

  // 6) out = P * vpT^T, causal klimit, split-K (24 slots: heavy halves first)
  gemm_bt<0, 1><<<dim3(24, H / 128, B), 256, 0, stream>>>(
      Sb, vpT, out, T, T, T, H,
      (long long)T * T, (long long)H * T, (long long)T * H,
      1.f, 0, 1, 0, nullptr);
}